// Round 1
// baseline (1876.165 us; speedup 1.0000x reference)
//
#include <hip/hip_runtime.h>
#include <stdint.h>

#define N_SLOTS   65536
#define KEY_DIM   64
#define VAL_DIM   64
#define N_QUERIES 8192
#define TOPK      4
#define LR        1e-3f
#define MOMENTUM  0.9f
#define WD        1e-4f

#define NCHUNK 8
#define CHUNK  (N_SLOTS / NCHUNK)   /* 8192 slots per block */
#define BQ 64                       /* queries per block */
#define BS 128                      /* slot tile */
#define TQ 4                        /* queries per thread */
#define TS 8                        /* slots per thread */
/* block: 256 threads = 16 ty (q) x 16 tx (s) */

// XOR swizzle: keeps 4-aligned tuples contiguous (b128-safe), makes transpose
// writes and fragment reads <=2-way bank conflicted (2-way is free on CDNA4).
__device__ __forceinline__ int swzcol(int s, int k) {
    return (s ^ ((s & 32) >> 3)) ^ (k & 0x1C);
}

__device__ __forceinline__ uint64_t ord64(double d) {
    uint64_t u = (uint64_t)__double_as_longlong(d);
    return (u & 0x8000000000000000ull) ? ~u : (u | 0x8000000000000000ull);
}

__device__ __forceinline__ void ins4(uint64_t* t, uint64_t key) {
    if (key > t[3]) {
        t[3] = key;
        if (t[3] > t[2]) { uint64_t x = t[2]; t[2] = t[3]; t[3] = x; }
        if (t[2] > t[1]) { uint64_t x = t[1]; t[1] = t[2]; t[2] = x; }
        if (t[1] > t[0]) { uint64_t x = t[0]; t[0] = t[1]; t[1] = x; }
    }
}

__device__ __forceinline__ void cswap(uint64_t& x, uint64_t& y) {
    uint64_t hi = x > y ? x : y;
    uint64_t lo = x > y ? y : x;
    x = hi; y = lo;
}

// merge two descending sorted-4 lists -> descending top-4 of union (bitonic)
__device__ __forceinline__ void merge4(uint64_t* a, uint64_t b0, uint64_t b1,
                                       uint64_t b2, uint64_t b3) {
    uint64_t m0 = a[0] > b3 ? a[0] : b3;
    uint64_t m1 = a[1] > b2 ? a[1] : b2;
    uint64_t m2 = a[2] > b1 ? a[2] : b1;
    uint64_t m3 = a[3] > b0 ? a[3] : b0;
    cswap(m0, m2); cswap(m1, m3); cswap(m0, m1); cswap(m2, m3);
    a[0] = m0; a[1] = m1; a[2] = m2; a[3] = m3;
}

__global__ __launch_bounds__(256, 2) void k1_sim_topk(
        const float* __restrict__ queries, const float* __restrict__ keys,
        uint64_t* __restrict__ part) {
    __shared__ float sQ[KEY_DIM][BQ];   // 16 KiB, k-major, swizzled
    __shared__ float sK[KEY_DIM][BS];   // 32 KiB, k-major, swizzled

    const int tid = threadIdx.x;
    const int tx = tid & 15;
    const int ty = tid >> 4;
    const int qblock = blockIdx.x;      // 0..127
    const int chunk  = blockIdx.y;      // 0..7

    // ---- stage Q tile (64 rows x 64 dims), transposed to k-major ----
    {
        const float4* src = (const float4*)(queries + (size_t)qblock * BQ * KEY_DIM);
        #pragma unroll
        for (int i = 0; i < (BQ * KEY_DIM / 4) / 256; ++i) {   // 4 iters
            int idx4 = tid + i * 256;
            int row = idx4 >> 4;
            int c4  = idx4 & 15;
            float4 v = src[idx4];
            sQ[c4 * 4 + 0][swzcol(row, c4 * 4 + 0)] = v.x;
            sQ[c4 * 4 + 1][swzcol(row, c4 * 4 + 1)] = v.y;
            sQ[c4 * 4 + 2][swzcol(row, c4 * 4 + 2)] = v.z;
            sQ[c4 * 4 + 3][swzcol(row, c4 * 4 + 3)] = v.w;
        }
    }

    uint64_t t4[TQ][4];
    #pragma unroll
    for (int a = 0; a < TQ; ++a) {
        #pragma unroll
        for (int j = 0; j < 4; ++j) t4[a][j] = 0ull;
    }

    const int q0 = ty * TQ;
    const int s0 = tx * TS;

    for (int st = 0; st < CHUNK / BS; ++st) {   // 64 slot-tiles
        __syncthreads();   // previous sK fully consumed
        {
            const float4* src = (const float4*)(keys +
                (size_t)(chunk * CHUNK + st * BS) * KEY_DIM);
            #pragma unroll
            for (int i = 0; i < 8; ++i) {       // 128 rows x 16 float4
                int idx4 = tid + i * 256;
                int row = idx4 >> 4;
                int c4  = idx4 & 15;
                float4 v = src[idx4];
                sK[c4 * 4 + 0][swzcol(row, c4 * 4 + 0)] = v.x;
                sK[c4 * 4 + 1][swzcol(row, c4 * 4 + 1)] = v.y;
                sK[c4 * 4 + 2][swzcol(row, c4 * 4 + 2)] = v.z;
                sK[c4 * 4 + 3][swzcol(row, c4 * 4 + 3)] = v.w;
            }
        }
        __syncthreads();

        double acc[TQ][TS];
        #pragma unroll
        for (int a = 0; a < TQ; ++a) {
            #pragma unroll
            for (int b = 0; b < TS; ++b) acc[a][b] = 0.0;
        }

        #pragma unroll 4
        for (int k = 0; k < KEY_DIM; ++k) {
            float4 qv  = *(const float4*)&sQ[k][swzcol(q0, k)];
            float4 kv0 = *(const float4*)&sK[k][swzcol(s0, k)];
            float4 kv1 = *(const float4*)&sK[k][swzcol(s0 + 4, k)];
            double qa[TQ] = {(double)qv.x, (double)qv.y, (double)qv.z, (double)qv.w};
            double kb[TS] = {(double)kv0.x, (double)kv0.y, (double)kv0.z, (double)kv0.w,
                             (double)kv1.x, (double)kv1.y, (double)kv1.z, (double)kv1.w};
            #pragma unroll
            for (int a = 0; a < TQ; ++a) {
                #pragma unroll
                for (int b = 0; b < TS; ++b)
                    acc[a][b] = fma(qa[a], kb[b], acc[a][b]);
            }
        }

        const int sbase = chunk * CHUNK + st * BS + s0;
        #pragma unroll
        for (int a = 0; a < TQ; ++a) {
            #pragma unroll
            for (int b = 0; b < TS; ++b) {
                uint64_t key = (ord64(acc[a][b]) & 0xFFFFFFFFFFFF0000ull)
                             | (uint64_t)((~(uint32_t)(sbase + b)) & 0xFFFFu);
                ins4(t4[a], key);
            }
        }
    }

    // butterfly merge across the 16 slot-lanes (tx)
    #pragma unroll
    for (int m = 1; m <= 8; m <<= 1) {
        #pragma unroll
        for (int a = 0; a < TQ; ++a) {
            uint64_t b0 = (uint64_t)__shfl_xor((unsigned long long)t4[a][0], m, 64);
            uint64_t b1 = (uint64_t)__shfl_xor((unsigned long long)t4[a][1], m, 64);
            uint64_t b2 = (uint64_t)__shfl_xor((unsigned long long)t4[a][2], m, 64);
            uint64_t b3 = (uint64_t)__shfl_xor((unsigned long long)t4[a][3], m, 64);
            merge4(t4[a], b0, b1, b2, b3);
        }
    }

    if (tx == 0) {
        #pragma unroll
        for (int a = 0; a < TQ; ++a) {
            int q = qblock * BQ + q0 + a;
            uint64_t* dst = part + ((size_t)q * NCHUNK + chunk) * 4;
            dst[0] = t4[a][0]; dst[1] = t4[a][1];
            dst[2] = t4[a][2]; dst[3] = t4[a][3];
        }
    }
}

__global__ void k2_merge(const uint64_t* __restrict__ part,
                         int* __restrict__ idx_int, float* __restrict__ idx_f) {
    int q = blockIdx.x * 256 + threadIdx.x;
    if (q >= N_QUERIES) return;
    uint64_t t[4] = {0ull, 0ull, 0ull, 0ull};
    const uint64_t* p = part + (size_t)q * NCHUNK * 4;
    #pragma unroll
    for (int i = 0; i < NCHUNK * 4; ++i) ins4(t, p[i]);
    #pragma unroll
    for (int j = 0; j < 4; ++j) {
        int slot = (int)((~(uint32_t)t[j]) & 0xFFFFu);
        idx_int[q * TOPK + j] = slot;
        idx_f[q * TOPK + j] = (float)slot;   // out buffer is read as f32
    }
}

__global__ void k3_gather_scatter(const int* __restrict__ idx_int,
                                  const float* __restrict__ vals,
                                  const float* __restrict__ grads,
                                  float* __restrict__ retrieved,
                                  float* __restrict__ slot_grads,
                                  float* __restrict__ counts) {
    int e = blockIdx.x * 256 + threadIdx.x;   // < N_QUERIES*TOPK*VAL_DIM
    int qr = e >> 6;          // q*TOPK + r
    int d  = e & 63;
    int slot = idx_int[qr];
    retrieved[e] = vals[slot * VAL_DIM + d];          // pre-update vals
    atomicAdd(&slot_grads[slot * VAL_DIM + d], grads[e]);
    if (d == 0) atomicAdd(&counts[slot], 1.0f);
}

__global__ void k4_update(const float* __restrict__ vals,
                          const float* __restrict__ mom,
                          const float* __restrict__ slot_grads,
                          const float* __restrict__ counts,
                          float* __restrict__ new_vals,
                          float* __restrict__ new_mom) {
    int e = blockIdx.x * 256 + threadIdx.x;   // < N_SLOTS*VAL_DIM
    int slot = e >> 6;
    float c = counts[slot];
    float g = slot_grads[e];
    float avg = g / fmaxf(c, 1.0f);           // g==0 when c==0 -> 0, matches ref
    float nm = MOMENTUM * mom[e] + avg;
    float v = vals[e];
    float nv = v + ((c > 0.0f) ? (-LR * (nm + WD * v)) : 0.0f);
    new_vals[e] = nv;
    new_mom[e] = nm;
}

__global__ void k0_zero(float* __restrict__ p, int n) {
    int i = blockIdx.x * 256 + threadIdx.x;
    if (i < n) p[i] = 0.0f;
}

extern "C" void kernel_launch(void* const* d_in, const int* in_sizes, int n_in,
                              void* d_out, int out_size, void* d_ws, size_t ws_size,
                              hipStream_t stream) {
    const float* queries = (const float*)d_in[0];
    const float* grads   = (const float*)d_in[1];
    const float* keys    = (const float*)d_in[2];
    const float* vals    = (const float*)d_in[3];
    const float* mom     = (const float*)d_in[4];

    float* out = (float*)d_out;
    float* retrieved = out;                                        // 8192*4*64
    float* idx_f     = retrieved + (size_t)N_QUERIES * TOPK * VAL_DIM; // 8192*4
    float* new_vals  = idx_f + (size_t)N_QUERIES * TOPK;           // 65536*64
    float* new_mom   = new_vals + (size_t)N_SLOTS * VAL_DIM;       // 65536*64

    float*    slot_grads = (float*)d_ws;                           // 16 MiB
    float*    counts     = slot_grads + (size_t)N_SLOTS * VAL_DIM; // 256 KiB
    uint64_t* part       = (uint64_t*)(counts + N_SLOTS);          // 2 MiB (8B aligned)
    int*      idx_int    = (int*)(part + (size_t)N_QUERIES * NCHUNK * 4);

    int nzero = N_SLOTS * VAL_DIM + N_SLOTS;
    hipLaunchKernelGGL(k0_zero, dim3((nzero + 255) / 256), dim3(256), 0, stream,
                       slot_grads, nzero);
    hipLaunchKernelGGL(k1_sim_topk, dim3(N_QUERIES / BQ, NCHUNK), dim3(256), 0, stream,
                       queries, keys, part);
    hipLaunchKernelGGL(k2_merge, dim3(N_QUERIES / 256), dim3(256), 0, stream,
                       part, idx_int, idx_f);
    hipLaunchKernelGGL(k3_gather_scatter,
                       dim3(N_QUERIES * TOPK * VAL_DIM / 256), dim3(256), 0, stream,
                       idx_int, vals, grads, retrieved, slot_grads, counts);
    hipLaunchKernelGGL(k4_update, dim3(N_SLOTS * VAL_DIM / 256), dim3(256), 0, stream,
                       vals, mom, slot_grads, counts, new_vals, new_mom);
}

// Round 2
// 321.379 us; speedup vs baseline: 5.8379x; 5.8379x over previous
//
#include <hip/hip_runtime.h>
#include <hip/hip_bf16.h>
#include <stdint.h>

#define N_SLOTS   65536
#define KEY_DIM   64
#define VAL_DIM   64
#define N_QUERIES 8192
#define TOPK      4
#define LR        1e-3f
#define MOMENTUM  0.9f
#define WD        1e-4f

#define NCHUNK 8
#define CHUNK  (N_SLOTS / NCHUNK)     /* 8192 slots per chunk */
#define TILE_SLOTS 128                /* slots staged per LDS tile */
#define TILES_PER_CHUNK (CHUNK / TILE_SLOTS)   /* 64 */
#define SUBT (TILE_SLOTS / 16)        /* 8 subtiles of 16 slots */
#define QPB 128                       /* queries per block (4 waves x 2 qtiles x 16) */

typedef __attribute__((ext_vector_type(8))) __bf16 bf16x8;
typedef __attribute__((ext_vector_type(4))) float  f32x4;
union B16 { uint4 u; bf16x8 b; };

__device__ __forceinline__ uint32_t ord32(float f) {
    uint32_t u = __float_as_uint(f);
    return (u & 0x80000000u) ? ~u : (u | 0x80000000u);
}
__device__ __forceinline__ uint64_t ord64(double d) {
    uint64_t u = (uint64_t)__double_as_longlong(d);
    return (u & 0x8000000000000000ull) ? ~u : (u | 0x8000000000000000ull);
}
__device__ __forceinline__ void ins4(uint64_t* t, uint64_t key) {
    if (key > t[3]) {
        t[3] = key;
        if (t[3] > t[2]) { uint64_t x = t[2]; t[2] = t[3]; t[3] = x; }
        if (t[2] > t[1]) { uint64_t x = t[1]; t[1] = t[2]; t[2] = x; }
        if (t[1] > t[0]) { uint64_t x = t[0]; t[0] = t[1]; t[1] = x; }
    }
}
__device__ __forceinline__ void cswap(uint64_t& x, uint64_t& y) {
    uint64_t hi = x > y ? x : y;
    uint64_t lo = x > y ? y : x;
    x = hi; y = lo;
}
__device__ __forceinline__ void merge4(uint64_t* a, uint64_t b0, uint64_t b1,
                                       uint64_t b2, uint64_t b3) {
    uint64_t m0 = a[0] > b3 ? a[0] : b3;
    uint64_t m1 = a[1] > b2 ? a[1] : b2;
    uint64_t m2 = a[2] > b1 ? a[2] : b1;
    uint64_t m3 = a[3] > b0 ? a[3] : b0;
    cswap(m0, m2); cswap(m1, m3); cswap(m0, m1); cswap(m2, m3);
    a[0] = m0; a[1] = m1; a[2] = m2; a[3] = m3;
}

__device__ __forceinline__ void split_bf16(float x, ushort& h, ushort& l) {
    __hip_bfloat16 hb = __float2bfloat16(x);
    float hf = __bfloat162float(hb);
    __hip_bfloat16 lb = __float2bfloat16(x - hf);
    h = *reinterpret_cast<const ushort*>(&hb);
    l = *reinterpret_cast<const ushort*>(&lb);
}

__device__ __forceinline__ void gload16(const void* g, void* l) {
    __builtin_amdgcn_global_load_lds(
        (const __attribute__((address_space(1))) uint32_t*)g,
        (__attribute__((address_space(3))) uint32_t*)l, 16, 0, 0);
}

// ---- split K into bf16 hi/lo, pre-swizzled tiled layout ----
// kpack layout (uint4 units of 8 bf16): tile = slot/128, r = slot%128:
//   unit = tile*2048 + h*1024 + r*8 + (k8 ^ (r&7))
__global__ void kA_split_k(const float* __restrict__ keys, uint4* __restrict__ kpack) {
    int e = blockIdx.x * 256 + threadIdx.x;     // slot*8 + k8
    int slot = e >> 3, k8 = e & 7;
    const float4* src = (const float4*)(keys + (size_t)slot * KEY_DIM + k8 * 8);
    float4 a = src[0], b = src[1];
    float x[8] = {a.x, a.y, a.z, a.w, b.x, b.y, b.z, b.w};
    ushort hh[8], ll[8];
    #pragma unroll
    for (int i = 0; i < 8; ++i) split_bf16(x[i], hh[i], ll[i]);
    uint4 hw, lw;
    hw.x = hh[0] | ((uint32_t)hh[1] << 16); hw.y = hh[2] | ((uint32_t)hh[3] << 16);
    hw.z = hh[4] | ((uint32_t)hh[5] << 16); hw.w = hh[6] | ((uint32_t)hh[7] << 16);
    lw.x = ll[0] | ((uint32_t)ll[1] << 16); lw.y = ll[2] | ((uint32_t)ll[3] << 16);
    lw.z = ll[4] | ((uint32_t)ll[5] << 16); lw.w = ll[6] | ((uint32_t)ll[7] << 16);
    int tile = slot >> 7, r = slot & 127;
    int k8s = k8 ^ (r & 7);
    kpack[(size_t)tile * 2048 + r * 8 + k8s] = hw;
    kpack[(size_t)tile * 2048 + 1024 + r * 8 + k8s] = lw;
}

// ---- split Q into bf16 hi/lo, plain row-major ----
__global__ void kA_split_q(const float* __restrict__ queries,
                           uint4* __restrict__ qhi, uint4* __restrict__ qlo) {
    int e = blockIdx.x * 256 + threadIdx.x;     // q*8 + k8
    const float4* src = (const float4*)(queries + (size_t)e * 8);
    float4 a = src[0], b = src[1];
    float x[8] = {a.x, a.y, a.z, a.w, b.x, b.y, b.z, b.w};
    ushort hh[8], ll[8];
    #pragma unroll
    for (int i = 0; i < 8; ++i) split_bf16(x[i], hh[i], ll[i]);
    uint4 hw, lw;
    hw.x = hh[0] | ((uint32_t)hh[1] << 16); hw.y = hh[2] | ((uint32_t)hh[3] << 16);
    hw.z = hh[4] | ((uint32_t)hh[5] << 16); hw.w = hh[6] | ((uint32_t)hh[7] << 16);
    lw.x = ll[0] | ((uint32_t)ll[1] << 16); lw.y = ll[2] | ((uint32_t)ll[3] << 16);
    lw.z = ll[4] | ((uint32_t)ll[5] << 16); lw.w = ll[6] | ((uint32_t)ll[7] << 16);
    qhi[e] = hw;
    qlo[e] = lw;
}

// ---- MFMA screen: C = slots x queries, fused top-4-tiles per lane ----
__global__ __launch_bounds__(256, 2) void k1_screen(
        const uint4* __restrict__ qhi, const uint4* __restrict__ qlo,
        const uint4* __restrict__ kpack, uint4* __restrict__ cand) {
    __shared__ uint4 sbuf[2][2048];             // 64 KiB double buffer

    const int tid = threadIdx.x;
    const int w = tid >> 6, lane = tid & 63;
    const int lcol = lane & 15, lrow = lane >> 4;
    const int qblock = blockIdx.x;              // 64
    const int chunk  = blockIdx.y;              // 8

    // loop-invariant B fragments (queries), hi/lo x 2 k-steps x 2 qtiles
    bf16x8 Bh[2][2], Bl[2][2];
    #pragma unroll
    for (int j = 0; j < 2; ++j) {
        #pragma unroll
        for (int ks = 0; ks < 2; ++ks) {
            int q = qblock * QPB + w * 32 + j * 16 + lcol;
            int u = q * 8 + lrow + ks * 4;
            B16 th, tl; th.u = qhi[u]; tl.u = qlo[u];
            Bh[j][ks] = th.b; Bl[j][ks] = tl.b;
        }
    }

    uint64_t tk[2][4];
    f32x4    tv[2][4];
    #pragma unroll
    for (int j = 0; j < 2; ++j)
        #pragma unroll
        for (int e = 0; e < 4; ++e) {
            tk[j][e] = 0ull;
            tv[j][e] = (f32x4){-3e38f, -3e38f, -3e38f, -3e38f};
        }

    const uint4* gbase = kpack + (size_t)(chunk * TILES_PER_CHUNK) * 2048;

#define STAGE(tt, bb) do {                                                   \
        const uint4* gg = gbase + (size_t)(tt) * 2048 + w * 512 + lane;      \
        _Pragma("unroll")                                                    \
        for (int i_ = 0; i_ < 8; ++i_)                                       \
            gload16((const void*)(gg + i_ * 64), (void*)&sbuf[bb][w * 512 + i_ * 64]); \
    } while (0)

    STAGE(0, 0);

    for (int t = 0; t < TILES_PER_CHUNK; ++t) {
        if (t < TILES_PER_CHUNK - 1) STAGE(t + 1, (t + 1) & 1);
        __syncthreads();                        // staging of tile t complete
        const uint4* sb = sbuf[t & 1];

        for (int sub = 0; sub < SUBT; ++sub) {
            int r = sub * 16 + lcol;
            int base = r * 8;
            int x0 = lrow ^ (r & 7);
            int x1 = (lrow + 4) ^ (r & 7);
            B16 ah0, ah1, al0, al1;
            ah0.u = sb[base + x0];
            ah1.u = sb[base + x1];
            al0.u = sb[1024 + base + x0];
            al1.u = sb[1024 + base + x1];
            int stid = t * SUBT + sub;          // 0..511 within chunk

            #pragma unroll
            for (int j = 0; j < 2; ++j) {
                f32x4 acc = {0.f, 0.f, 0.f, 0.f};
                acc = __builtin_amdgcn_mfma_f32_16x16x32_bf16(ah0.b, Bh[j][0], acc, 0, 0, 0);
                acc = __builtin_amdgcn_mfma_f32_16x16x32_bf16(ah1.b, Bh[j][1], acc, 0, 0, 0);
                acc = __builtin_amdgcn_mfma_f32_16x16x32_bf16(ah0.b, Bl[j][0], acc, 0, 0, 0);
                acc = __builtin_amdgcn_mfma_f32_16x16x32_bf16(al0.b, Bh[j][0], acc, 0, 0, 0);
                acc = __builtin_amdgcn_mfma_f32_16x16x32_bf16(ah1.b, Bl[j][1], acc, 0, 0, 0);
                acc = __builtin_amdgcn_mfma_f32_16x16x32_bf16(al1.b, Bh[j][1], acc, 0, 0, 0);

                float m = fmaxf(fmaxf(acc[0], acc[1]), fmaxf(acc[2], acc[3]));
                uint64_t key = ((uint64_t)ord32(m) << 16) | (uint32_t)stid;
                if (key > tk[j][3]) {
                    tk[j][3] = key; tv[j][3] = acc;
                    if (tk[j][3] > tk[j][2]) { uint64_t k_ = tk[j][2]; tk[j][2] = tk[j][3]; tk[j][3] = k_;
                                               f32x4 v_ = tv[j][2]; tv[j][2] = tv[j][3]; tv[j][3] = v_; }
                    if (tk[j][2] > tk[j][1]) { uint64_t k_ = tk[j][1]; tk[j][1] = tk[j][2]; tk[j][2] = k_;
                                               f32x4 v_ = tv[j][1]; tv[j][1] = tv[j][2]; tv[j][2] = v_; }
                    if (tk[j][1] > tk[j][0]) { uint64_t k_ = tk[j][0]; tk[j][0] = tk[j][1]; tk[j][1] = k_;
                                               f32x4 v_ = tv[j][0]; tv[j][0] = tv[j][1]; tv[j][1] = v_; }
                }
            }
        }
        __syncthreads();                        // all reads of buf done before overwrite
    }
#undef STAGE

    // extract per-lane top-4 slots from the 4 kept tiles, then merge row-groups
    #pragma unroll
    for (int j = 0; j < 2; ++j) {
        uint64_t s4[4] = {0ull, 0ull, 0ull, 0ull};
        #pragma unroll
        for (int e = 0; e < 4; ++e) {
            int stid = (int)(tk[j][e] & 0xFFFFu);
            int sb0 = chunk * CHUNK + stid * 16 + lrow * 4;
            #pragma unroll
            for (int rr = 0; rr < 4; ++rr) {
                int slot = sb0 + rr;
                uint64_t skey = ((uint64_t)ord32(tv[j][e][rr]) << 16)
                              | (uint32_t)((~(uint32_t)slot) & 0xFFFFu);
                ins4(s4, skey);
            }
        }
        #pragma unroll
        for (int m = 16; m <= 32; m <<= 1) {
            uint64_t b0 = (uint64_t)__shfl_xor((unsigned long long)s4[0], m, 64);
            uint64_t b1 = (uint64_t)__shfl_xor((unsigned long long)s4[1], m, 64);
            uint64_t b2 = (uint64_t)__shfl_xor((unsigned long long)s4[2], m, 64);
            uint64_t b3 = (uint64_t)__shfl_xor((unsigned long long)s4[3], m, 64);
            merge4(s4, b0, b1, b2, b3);
        }
        if (lane < 16) {
            int q = qblock * QPB + w * 32 + j * 16 + lane;
            uint4 c;
            c.x = (~(uint32_t)s4[0]) & 0xFFFFu;
            c.y = (~(uint32_t)s4[1]) & 0xFFFFu;
            c.z = (~(uint32_t)s4[2]) & 0xFFFFu;
            c.w = (~(uint32_t)s4[3]) & 0xFFFFu;
            cand[(size_t)q * NCHUNK + chunk] = c;
        }
    }
}

// ---- exact f64 rescore of 32 candidates per query ----
__global__ void k2_rescore(const uint4* __restrict__ cand,
                           const float* __restrict__ queries,
                           const float* __restrict__ keys,
                           int* __restrict__ idx_int, float* __restrict__ idx_f) {
    int tid = threadIdx.x;
    int w = tid >> 6, lane = tid & 63;
    int q = blockIdx.x * 4 + w;
    int h = lane >> 5, c = lane & 31;

    uint4 cv = cand[(size_t)q * NCHUNK + (c >> 2)];
    uint32_t slot = (c & 3) == 0 ? cv.x : (c & 3) == 1 ? cv.y : (c & 3) == 2 ? cv.z : cv.w;

    const float* krow = keys + (size_t)slot * KEY_DIM + h * 32;
    const float* qrow = queries + (size_t)q * KEY_DIM + h * 32;
    double acc = 0.0;
    #pragma unroll
    for (int i = 0; i < 32; ++i)
        acc = fma((double)qrow[i], (double)krow[i], acc);
    acc += __shfl_xor(acc, 32, 64);             // combine dim halves

    uint64_t key = (ord64(acc) & 0xFFFFFFFFFFFF0000ull)
                 | (uint64_t)((~slot) & 0xFFFFu);
    uint64_t s4[4] = {key, 0ull, 0ull, 0ull};
    #pragma unroll
    for (int m = 1; m <= 16; m <<= 1) {         // stay within the 32-lane half
        uint64_t b0 = (uint64_t)__shfl_xor((unsigned long long)s4[0], m, 64);
        uint64_t b1 = (uint64_t)__shfl_xor((unsigned long long)s4[1], m, 64);
        uint64_t b2 = (uint64_t)__shfl_xor((unsigned long long)s4[2], m, 64);
        uint64_t b3 = (uint64_t)__shfl_xor((unsigned long long)s4[3], m, 64);
        merge4(s4, b0, b1, b2, b3);
    }
    if (lane == 0) {
        #pragma unroll
        for (int r = 0; r < 4; ++r) {
            int s = (int)((~(uint32_t)s4[r]) & 0xFFFFu);
            idx_int[q * TOPK + r] = s;
            idx_f[q * TOPK + r] = (float)s;
        }
    }
}

__global__ void k3_gather_scatter(const int* __restrict__ idx_int,
                                  const float* __restrict__ vals,
                                  const float* __restrict__ grads,
                                  float* __restrict__ retrieved,
                                  float* __restrict__ slot_grads,
                                  float* __restrict__ counts) {
    int e = blockIdx.x * 256 + threadIdx.x;
    int qr = e >> 6;
    int d  = e & 63;
    int slot = idx_int[qr];
    retrieved[e] = vals[slot * VAL_DIM + d];
    atomicAdd(&slot_grads[slot * VAL_DIM + d], grads[e]);
    if (d == 0) atomicAdd(&counts[slot], 1.0f);
}

__global__ void k4_update(const float* __restrict__ vals,
                          const float* __restrict__ mom,
                          const float* __restrict__ slot_grads,
                          const float* __restrict__ counts,
                          float* __restrict__ new_vals,
                          float* __restrict__ new_mom) {
    int e = blockIdx.x * 256 + threadIdx.x;
    int slot = e >> 6;
    float c = counts[slot];
    float g = slot_grads[e];
    float avg = g / fmaxf(c, 1.0f);
    float nm = MOMENTUM * mom[e] + avg;
    float v = vals[e];
    float nv = v + ((c > 0.0f) ? (-LR * (nm + WD * v)) : 0.0f);
    new_vals[e] = nv;
    new_mom[e] = nm;
}

__global__ void k0_zero(float* __restrict__ p, int n) {
    int i = blockIdx.x * 256 + threadIdx.x;
    if (i < n) p[i] = 0.0f;
}

extern "C" void kernel_launch(void* const* d_in, const int* in_sizes, int n_in,
                              void* d_out, int out_size, void* d_ws, size_t ws_size,
                              hipStream_t stream) {
    const float* queries = (const float*)d_in[0];
    const float* grads   = (const float*)d_in[1];
    const float* keys    = (const float*)d_in[2];
    const float* vals    = (const float*)d_in[3];
    const float* mom     = (const float*)d_in[4];

    float* out = (float*)d_out;
    float* retrieved = out;
    float* idx_f     = retrieved + (size_t)N_QUERIES * TOPK * VAL_DIM;
    float* new_vals  = idx_f + (size_t)N_QUERIES * TOPK;
    float* new_mom   = new_vals + (size_t)N_SLOTS * VAL_DIM;

    float* slot_grads = (float*)d_ws;                             // 16 MiB
    float* counts     = slot_grads + (size_t)N_SLOTS * VAL_DIM;   // 256 KiB
    uint4* qhi   = (uint4*)(counts + N_SLOTS);                    // 1 MiB
    uint4* qlo   = qhi + (size_t)N_QUERIES * 8;                   // 1 MiB
    uint4* kpack = qlo + (size_t)N_QUERIES * 8;                   // 16 MiB
    uint4* cand  = kpack + (size_t)(N_SLOTS / TILE_SLOTS) * 2048; // 1 MiB
    int*   idx_int = (int*)(cand + (size_t)N_QUERIES * NCHUNK);   // 128 KiB

    int nzero = N_SLOTS * VAL_DIM + N_SLOTS;
    hipLaunchKernelGGL(k0_zero, dim3((nzero + 255) / 256), dim3(256), 0, stream,
                       slot_grads, nzero);
    hipLaunchKernelGGL(kA_split_q, dim3(N_QUERIES * 8 / 256), dim3(256), 0, stream,
                       queries, qhi, qlo);
    hipLaunchKernelGGL(kA_split_k, dim3(N_SLOTS * 8 / 256), dim3(256), 0, stream,
                       keys, kpack);
    hipLaunchKernelGGL(k1_screen, dim3(N_QUERIES / QPB, NCHUNK), dim3(256), 0, stream,
                       qhi, qlo, kpack, cand);
    hipLaunchKernelGGL(k2_rescore, dim3(N_QUERIES / 4), dim3(256), 0, stream,
                       cand, queries, keys, idx_int, idx_f);
    hipLaunchKernelGGL(k3_gather_scatter,
                       dim3(N_QUERIES * TOPK * VAL_DIM / 256), dim3(256), 0, stream,
                       idx_int, vals, grads, retrieved, slot_grads, counts);
    hipLaunchKernelGGL(k4_update, dim3(N_SLOTS * VAL_DIM / 256), dim3(256), 0, stream,
                       vals, mom, slot_grads, counts, new_vals, new_mom);
}

// Round 3
// 251.566 us; speedup vs baseline: 7.4579x; 1.2775x over previous
//
#include <hip/hip_runtime.h>
#include <stdint.h>

#define N_SLOTS   65536
#define KEY_DIM   64
#define VAL_DIM   64
#define N_QUERIES 8192
#define TOPK      4
#define LR        1e-3f
#define MOMENTUM  0.9f
#define WD        1e-4f

#define NCHUNK 8
#define CHUNK  (N_SLOTS / NCHUNK)     /* 8192 slots per chunk */
#define TILE_SLOTS 128
#define TILES_PER_CHUNK (CHUNK / TILE_SLOTS)   /* 64 */
#define SUBT 8                         /* 8 subtiles of 16 slots per tile */
#define QPB 128                        /* 4 waves x 2 qtiles x 16 */

typedef __attribute__((ext_vector_type(8))) _Float16 f16x8;
typedef __attribute__((ext_vector_type(4))) float    f32x4;
union F16 { uint4 u; f16x8 h; };
union F16A { uint4 u; _Float16 h[8]; };

__device__ __forceinline__ uint32_t ord32(float f) {
    uint32_t u = __float_as_uint(f);
    return (u & 0x80000000u) ? ~u : (u | 0x80000000u);
}
__device__ __forceinline__ uint64_t ord64(double d) {
    uint64_t u = (uint64_t)__double_as_longlong(d);
    return (u & 0x8000000000000000ull) ? ~u : (u | 0x8000000000000000ull);
}
__device__ __forceinline__ void ins4(uint64_t* t, uint64_t key) {
    if (key > t[3]) {
        t[3] = key;
        if (t[3] > t[2]) { uint64_t x = t[2]; t[2] = t[3]; t[3] = x; }
        if (t[2] > t[1]) { uint64_t x = t[1]; t[1] = t[2]; t[2] = x; }
        if (t[1] > t[0]) { uint64_t x = t[0]; t[0] = t[1]; t[1] = x; }
    }
}
__device__ __forceinline__ void cswap(uint64_t& x, uint64_t& y) {
    uint64_t hi = x > y ? x : y;
    uint64_t lo = x > y ? y : x;
    x = hi; y = lo;
}
__device__ __forceinline__ void merge4(uint64_t* a, uint64_t b0, uint64_t b1,
                                       uint64_t b2, uint64_t b3) {
    uint64_t m0 = a[0] > b3 ? a[0] : b3;
    uint64_t m1 = a[1] > b2 ? a[1] : b2;
    uint64_t m2 = a[2] > b1 ? a[2] : b1;
    uint64_t m3 = a[3] > b0 ? a[3] : b0;
    cswap(m0, m2); cswap(m1, m3); cswap(m0, m1); cswap(m2, m3);
    a[0] = m0; a[1] = m1; a[2] = m2; a[3] = m3;
}

__device__ __forceinline__ void gload16(const void* g, void* l) {
    __builtin_amdgcn_global_load_lds(
        (const __attribute__((address_space(1))) uint32_t*)g,
        (__attribute__((address_space(3))) uint32_t*)l, 16, 0, 0);
}

// ---- f32 -> f16, K pre-swizzled tiled layout (uint4 = 8 f16) ----
// unit = tile*1024 + r*8 + (k8 ^ (r&7)),  tile = slot/128, r = slot%128
__global__ void kA_split_k(const float* __restrict__ keys, uint4* __restrict__ kpack) {
    int e = blockIdx.x * 256 + threadIdx.x;     // slot*8 + k8
    int slot = e >> 3, k8 = e & 7;
    const float4* src = (const float4*)(keys + (size_t)slot * KEY_DIM + k8 * 8);
    float4 a = src[0], b = src[1];
    F16A u;
    u.h[0] = (_Float16)a.x; u.h[1] = (_Float16)a.y;
    u.h[2] = (_Float16)a.z; u.h[3] = (_Float16)a.w;
    u.h[4] = (_Float16)b.x; u.h[5] = (_Float16)b.y;
    u.h[6] = (_Float16)b.z; u.h[7] = (_Float16)b.w;
    int tile = slot >> 7, r = slot & 127;
    kpack[(size_t)tile * 1024 + r * 8 + (k8 ^ (r & 7))] = u.u;
}

__global__ void kA_split_q(const float* __restrict__ queries, uint4* __restrict__ qpack) {
    int e = blockIdx.x * 256 + threadIdx.x;     // q*8 + k8
    const float4* src = (const float4*)(queries + (size_t)e * 8);
    float4 a = src[0], b = src[1];
    F16A u;
    u.h[0] = (_Float16)a.x; u.h[1] = (_Float16)a.y;
    u.h[2] = (_Float16)a.z; u.h[3] = (_Float16)a.w;
    u.h[4] = (_Float16)b.x; u.h[5] = (_Float16)b.y;
    u.h[6] = (_Float16)b.z; u.h[7] = (_Float16)b.w;
    qpack[e] = u.u;
}

// ---- 1-pass f16 MFMA screen: per-lane top-4 (group-max, group-id), no payload ----
__global__ __launch_bounds__(256, 2) void k1_screen(
        const uint4* __restrict__ qpack, const uint4* __restrict__ kpack,
        uint32_t* __restrict__ cand) {
    __shared__ uint4 sbuf[2048];                // 32 KiB double buffer (2 x 16 KiB)

    const int tid = threadIdx.x;
    const int w = tid >> 6, lane = tid & 63;
    const int lcol = lane & 15, lrow = lane >> 4;
    const int qblock = blockIdx.x;              // 64
    const int chunk  = blockIdx.y;              // 8

    // loop-invariant B fragments (queries): 2 qtiles x 2 k-steps
    f16x8 B[2][2];
    #pragma unroll
    for (int j = 0; j < 2; ++j) {
        #pragma unroll
        for (int ks = 0; ks < 2; ++ks) {
            int q = qblock * QPB + w * 32 + j * 16 + lcol;
            F16 t; t.u = qpack[q * 8 + lrow + ks * 4];
            B[j][ks] = t.h;
        }
    }

    float    m_[2][4];
    uint32_t g_[2][4];
    #pragma unroll
    for (int j = 0; j < 2; ++j)
        #pragma unroll
        for (int e = 0; e < 4; ++e) { m_[j][e] = -3e38f; g_[j][e] = 0u; }

    const uint4* gbase = kpack + (size_t)(chunk * TILES_PER_CHUNK) * 1024;
    const int x0 = lrow ^ (lcol & 7);
    const int base_b = lcol * 128 + x0 * 16;    // invariant ds byte offset

#define STAGE(tt, bb) do {                                                    \
        const uint4* gg = gbase + (size_t)(tt) * 1024 + w * 256 + lane;       \
        char* ldst = (char*)sbuf + (bb) * 16384 + w * 4096;                   \
        _Pragma("unroll")                                                     \
        for (int i_ = 0; i_ < 4; ++i_)                                        \
            gload16((const void*)(gg + i_ * 64), (void*)(ldst + i_ * 1024));  \
    } while (0)

    STAGE(0, 0);

    for (int t = 0; t < TILES_PER_CHUNK; ++t) {
        if (t < TILES_PER_CHUNK - 1) STAGE(t + 1, (t + 1) & 1);
        __syncthreads();                        // staging of tile t complete
        const char* sbb = (const char*)sbuf + (t & 1) * 16384;

        #pragma unroll
        for (int sub = 0; sub < SUBT; ++sub) {
            uint4 ua0 = *(const uint4*)(sbb + base_b + sub * 2048);
            uint4 ua1 = *(const uint4*)(sbb + (base_b ^ 64) + sub * 2048);
            F16 a0, a1; a0.u = ua0; a1.u = ua1;
            uint32_t gid = (uint32_t)(t * SUBT + sub);   // 0..511

            #pragma unroll
            for (int j = 0; j < 2; ++j) {
                f32x4 acc = {0.f, 0.f, 0.f, 0.f};
                acc = __builtin_amdgcn_mfma_f32_16x16x32_f16(a0.h, B[j][0], acc, 0, 0, 0);
                acc = __builtin_amdgcn_mfma_f32_16x16x32_f16(a1.h, B[j][1], acc, 0, 0, 0);
                float m = fmaxf(fmaxf(fmaxf(acc[0], acc[1]), acc[2]), acc[3]);
                if (m > m_[j][3]) {
                    bool b2 = m > m_[j][2], b1 = m > m_[j][1], b0 = m > m_[j][0];
                    m_[j][3] = b2 ? m_[j][2] : m;  g_[j][3] = b2 ? g_[j][2] : gid;
                    m_[j][2] = b2 ? (b1 ? m_[j][1] : m) : m_[j][2];
                    g_[j][2] = b2 ? (b1 ? g_[j][1] : gid) : g_[j][2];
                    m_[j][1] = b1 ? (b0 ? m_[j][0] : m) : m_[j][1];
                    g_[j][1] = b1 ? (b0 ? g_[j][0] : gid) : g_[j][1];
                    m_[j][0] = b0 ? m : m_[j][0];  g_[j][0] = b0 ? gid : g_[j][0];
                }
            }
        }
        __syncthreads();                        // reads done before overwrite
    }
#undef STAGE

    // merge top-4 groups across the 4 lane-rows; emit 4 group ids per (q,chunk)
    #pragma unroll
    for (int j = 0; j < 2; ++j) {
        uint64_t s4[4];
        #pragma unroll
        for (int e = 0; e < 4; ++e)
            s4[e] = ((uint64_t)ord32(m_[j][e]) << 32)
                  | (uint64_t)(g_[j][e] * 4 + (uint32_t)lrow);
        #pragma unroll
        for (int m = 16; m <= 32; m <<= 1) {
            uint64_t b0 = (uint64_t)__shfl_xor((unsigned long long)s4[0], m, 64);
            uint64_t b1 = (uint64_t)__shfl_xor((unsigned long long)s4[1], m, 64);
            uint64_t b2 = (uint64_t)__shfl_xor((unsigned long long)s4[2], m, 64);
            uint64_t b3 = (uint64_t)__shfl_xor((unsigned long long)s4[3], m, 64);
            merge4(s4, b0, b1, b2, b3);
        }
        if (lane < 16) {
            int q = qblock * QPB + w * 32 + j * 16 + lane;
            uint4 c;
            c.x = (uint32_t)s4[0]; c.y = (uint32_t)s4[1];
            c.z = (uint32_t)s4[2]; c.w = (uint32_t)s4[3];
            *(uint4*)&cand[((size_t)q * NCHUNK + chunk) * 4] = c;
        }
    }
}

// ---- exact f64 rescore of 128 candidates per query (1 wave / query) ----
__global__ __launch_bounds__(256) void k2_rescore(
        const uint32_t* __restrict__ cand,
        const float* __restrict__ queries, const float* __restrict__ keys,
        int* __restrict__ idx_int, float* __restrict__ idx_f) {
    int w = threadIdx.x >> 6, lane = threadIdx.x & 63;
    int q = blockIdx.x * 4 + w;
    const float4* qrow = (const float4*)(queries + (size_t)q * KEY_DIM);

    uint64_t s4[4] = {0ull, 0ull, 0ull, 0ull};
    #pragma unroll
    for (int half = 0; half < 2; ++half) {
        int c = lane + half * 64;               // candidate 0..127
        int chunk = c >> 4, e = (c >> 2) & 3, rr = c & 3;
        uint32_t grow = cand[((size_t)q * NCHUNK + chunk) * 4 + e];
        int slot = chunk * CHUNK + (int)(grow >> 2) * 16 + (int)(grow & 3) * 4 + rr;
        const float4* krow = (const float4*)(keys + (size_t)slot * KEY_DIM);
        double acc = 0.0;
        #pragma unroll
        for (int u = 0; u < 16; ++u) {
            float4 qv = qrow[u], kv = krow[u];
            acc = fma((double)qv.x, (double)kv.x, acc);
            acc = fma((double)qv.y, (double)kv.y, acc);
            acc = fma((double)qv.z, (double)kv.z, acc);
            acc = fma((double)qv.w, (double)kv.w, acc);
        }
        uint64_t key = (ord64(acc) & 0xFFFFFFFFFFFF0000ull)
                     | (uint64_t)((~(uint32_t)slot) & 0xFFFFu);
        ins4(s4, key);
    }
    #pragma unroll
    for (int m = 1; m <= 32; m <<= 1) {
        uint64_t b0 = (uint64_t)__shfl_xor((unsigned long long)s4[0], m, 64);
        uint64_t b1 = (uint64_t)__shfl_xor((unsigned long long)s4[1], m, 64);
        uint64_t b2 = (uint64_t)__shfl_xor((unsigned long long)s4[2], m, 64);
        uint64_t b3 = (uint64_t)__shfl_xor((unsigned long long)s4[3], m, 64);
        merge4(s4, b0, b1, b2, b3);
    }
    if (lane == 0) {
        #pragma unroll
        for (int r = 0; r < 4; ++r) {
            int s = (int)((~(uint32_t)s4[r]) & 0xFFFFu);
            idx_int[q * TOPK + r] = s;
            idx_f[q * TOPK + r] = (float)s;
        }
    }
}

__global__ void k3_gather_scatter(const int* __restrict__ idx_int,
                                  const float* __restrict__ vals,
                                  const float* __restrict__ grads,
                                  float* __restrict__ retrieved,
                                  float* __restrict__ slot_grads,
                                  float* __restrict__ counts) {
    int e = blockIdx.x * 256 + threadIdx.x;
    int qr = e >> 6;
    int d  = e & 63;
    int slot = idx_int[qr];
    retrieved[e] = vals[slot * VAL_DIM + d];
    atomicAdd(&slot_grads[slot * VAL_DIM + d], grads[e]);
    if (d == 0) atomicAdd(&counts[slot], 1.0f);
}

__global__ void k4_update(const float* __restrict__ vals,
                          const float* __restrict__ mom,
                          const float* __restrict__ slot_grads,
                          const float* __restrict__ counts,
                          float* __restrict__ new_vals,
                          float* __restrict__ new_mom) {
    int e = blockIdx.x * 256 + threadIdx.x;
    int slot = e >> 6;
    float c = counts[slot];
    float g = slot_grads[e];
    float avg = g / fmaxf(c, 1.0f);
    float nm = MOMENTUM * mom[e] + avg;
    float v = vals[e];
    float nv = v + ((c > 0.0f) ? (-LR * (nm + WD * v)) : 0.0f);
    new_vals[e] = nv;
    new_mom[e] = nm;
}

__global__ void k0_zero(float* __restrict__ p, int n) {
    int i = blockIdx.x * 256 + threadIdx.x;
    if (i < n) p[i] = 0.0f;
}

extern "C" void kernel_launch(void* const* d_in, const int* in_sizes, int n_in,
                              void* d_out, int out_size, void* d_ws, size_t ws_size,
                              hipStream_t stream) {
    const float* queries = (const float*)d_in[0];
    const float* grads   = (const float*)d_in[1];
    const float* keys    = (const float*)d_in[2];
    const float* vals    = (const float*)d_in[3];
    const float* mom     = (const float*)d_in[4];

    float* out = (float*)d_out;
    float* retrieved = out;
    float* idx_f     = retrieved + (size_t)N_QUERIES * TOPK * VAL_DIM;
    float* new_vals  = idx_f + (size_t)N_QUERIES * TOPK;
    float* new_mom   = new_vals + (size_t)N_SLOTS * VAL_DIM;

    float*    slot_grads = (float*)d_ws;                            // 16 MiB
    float*    counts     = slot_grads + (size_t)N_SLOTS * VAL_DIM;  // 256 KiB
    uint4*    qpack  = (uint4*)(counts + N_SLOTS);                  // 1 MiB
    uint4*    kpack  = qpack + (size_t)N_QUERIES * 8;               // 8 MiB
    uint32_t* cand   = (uint32_t*)(kpack + (size_t)(N_SLOTS / TILE_SLOTS) * 1024); // 1 MiB
    int*      idx_int = (int*)(cand + (size_t)N_QUERIES * NCHUNK * 4);             // 128 KiB

    int nzero = N_SLOTS * VAL_DIM + N_SLOTS;
    hipLaunchKernelGGL(k0_zero, dim3((nzero + 255) / 256), dim3(256), 0, stream,
                       slot_grads, nzero);
    hipLaunchKernelGGL(kA_split_q, dim3(N_QUERIES * 8 / 256), dim3(256), 0, stream,
                       queries, qpack);
    hipLaunchKernelGGL(kA_split_k, dim3(N_SLOTS * 8 / 256), dim3(256), 0, stream,
                       keys, kpack);
    hipLaunchKernelGGL(k1_screen, dim3(N_QUERIES / QPB, NCHUNK), dim3(256), 0, stream,
                       qpack, kpack, cand);
    hipLaunchKernelGGL(k2_rescore, dim3(N_QUERIES / 4), dim3(256), 0, stream,
                       cand, queries, keys, idx_int, idx_f);
    hipLaunchKernelGGL(k3_gather_scatter,
                       dim3(N_QUERIES * TOPK * VAL_DIM / 256), dim3(256), 0, stream,
                       idx_int, vals, grads, retrieved, slot_grads, counts);
    hipLaunchKernelGGL(k4_update, dim3(N_SLOTS * VAL_DIM / 256), dim3(256), 0, stream,
                       vals, mom, slot_grads, counts, new_vals, new_mom);
}

// Round 4
// 249.750 us; speedup vs baseline: 7.5122x; 1.0073x over previous
//
#include <hip/hip_runtime.h>
#include <stdint.h>

#define N_SLOTS   65536
#define KEY_DIM   64
#define VAL_DIM   64
#define N_QUERIES 8192
#define TOPK      4
#define LR        1e-3f
#define MOMENTUM  0.9f
#define WD        1e-4f

#define NCHUNK 8
#define CHUNK  (N_SLOTS / NCHUNK)     /* 8192 slots per chunk */
#define TILE_SLOTS 128
#define TILES_PER_CHUNK (CHUNK / TILE_SLOTS)   /* 64 */
#define SUBT 8                         /* 8 subtiles of 16 slots per tile */
#define QPB 128                        /* 4 waves x 2 qtiles x 16 */

typedef __attribute__((ext_vector_type(8))) _Float16 f16x8;
typedef __attribute__((ext_vector_type(4))) float    f32x4;
union F16 { uint4 u; f16x8 h; };
union F16A { uint4 u; _Float16 h[8]; };

__device__ __forceinline__ uint32_t ord32(float f) {
    uint32_t u = __float_as_uint(f);
    return (u & 0x80000000u) ? ~u : (u | 0x80000000u);
}
__device__ __forceinline__ uint64_t ord64(double d) {
    uint64_t u = (uint64_t)__double_as_longlong(d);
    return (u & 0x8000000000000000ull) ? ~u : (u | 0x8000000000000000ull);
}
__device__ __forceinline__ void ins4(uint64_t* t, uint64_t key) {
    if (key > t[3]) {
        t[3] = key;
        if (t[3] > t[2]) { uint64_t x = t[2]; t[2] = t[3]; t[3] = x; }
        if (t[2] > t[1]) { uint64_t x = t[1]; t[1] = t[2]; t[2] = x; }
        if (t[1] > t[0]) { uint64_t x = t[0]; t[0] = t[1]; t[1] = x; }
    }
}
__device__ __forceinline__ void cswap(uint64_t& x, uint64_t& y) {
    uint64_t hi = x > y ? x : y;
    uint64_t lo = x > y ? y : x;
    x = hi; y = lo;
}
__device__ __forceinline__ void merge4(uint64_t* a, uint64_t b0, uint64_t b1,
                                       uint64_t b2, uint64_t b3) {
    uint64_t m0 = a[0] > b3 ? a[0] : b3;
    uint64_t m1 = a[1] > b2 ? a[1] : b2;
    uint64_t m2 = a[2] > b1 ? a[2] : b1;
    uint64_t m3 = a[3] > b0 ? a[3] : b0;
    cswap(m0, m2); cswap(m1, m3); cswap(m0, m1); cswap(m2, m3);
    a[0] = m0; a[1] = m1; a[2] = m2; a[3] = m3;
}

__device__ __forceinline__ void gload16(const void* g, void* l) {
    __builtin_amdgcn_global_load_lds(
        (const __attribute__((address_space(1))) uint32_t*)g,
        (__attribute__((address_space(3))) uint32_t*)l, 16, 0, 0);
}

// ---- f32 -> f16, K pre-swizzled tiled layout (uint4 = 8 f16) ----
// unit = tile*1024 + r*8 + (k8 ^ (r&7)),  tile = slot/128, r = slot%128
__global__ void kA_split_k(const float* __restrict__ keys, uint4* __restrict__ kpack) {
    int e = blockIdx.x * 256 + threadIdx.x;     // slot*8 + k8
    int slot = e >> 3, k8 = e & 7;
    const float4* src = (const float4*)(keys + (size_t)slot * KEY_DIM + k8 * 8);
    float4 a = src[0], b = src[1];
    F16A u;
    u.h[0] = (_Float16)a.x; u.h[1] = (_Float16)a.y;
    u.h[2] = (_Float16)a.z; u.h[3] = (_Float16)a.w;
    u.h[4] = (_Float16)b.x; u.h[5] = (_Float16)b.y;
    u.h[6] = (_Float16)b.z; u.h[7] = (_Float16)b.w;
    int tile = slot >> 7, r = slot & 127;
    kpack[(size_t)tile * 1024 + r * 8 + (k8 ^ (r & 7))] = u.u;
}

__global__ void kA_split_q(const float* __restrict__ queries, uint4* __restrict__ qpack) {
    int e = blockIdx.x * 256 + threadIdx.x;     // q*8 + k8
    const float4* src = (const float4*)(queries + (size_t)e * 8);
    float4 a = src[0], b = src[1];
    F16A u;
    u.h[0] = (_Float16)a.x; u.h[1] = (_Float16)a.y;
    u.h[2] = (_Float16)a.z; u.h[3] = (_Float16)a.w;
    u.h[4] = (_Float16)b.x; u.h[5] = (_Float16)b.y;
    u.h[6] = (_Float16)b.z; u.h[7] = (_Float16)b.w;
    qpack[e] = u.u;
}

// ---- 1-pass f16 MFMA screen, 2-phase pipelined (stage t+1 under compute t) ----
__global__ __launch_bounds__(256, 2) void k1_screen(
        const uint4* __restrict__ qpack, const uint4* __restrict__ kpack,
        uint32_t* __restrict__ cand) {
    __shared__ uint4 sbuf[2048];                // 32 KiB double buffer (2 x 16 KiB)

    const int tid = threadIdx.x;
    const int w = tid >> 6, lane = tid & 63;
    const int lcol = lane & 15, lrow = lane >> 4;
    const int qblock = blockIdx.x;              // 64
    const int chunk  = blockIdx.y;              // 8

    // loop-invariant B fragments (queries): 2 qtiles x 2 k-steps
    f16x8 B[2][2];
    #pragma unroll
    for (int j = 0; j < 2; ++j) {
        #pragma unroll
        for (int ks = 0; ks < 2; ++ks) {
            int q = qblock * QPB + w * 32 + j * 16 + lcol;
            F16 t; t.u = qpack[q * 8 + lrow + ks * 4];
            B[j][ks] = t.h;
        }
    }

    float    m_[2][4];
    uint32_t g_[2][4];
    #pragma unroll
    for (int j = 0; j < 2; ++j)
        #pragma unroll
        for (int e = 0; e < 4; ++e) { m_[j][e] = -3e38f; g_[j][e] = 0u; }

    const uint4* gbase = kpack + (size_t)(chunk * TILES_PER_CHUNK) * 1024;
    const int x0 = lrow ^ (lcol & 7);
    const int base_b = lcol * 128 + x0 * 16;    // invariant ds byte offset
    const f32x4 zacc = {0.f, 0.f, 0.f, 0.f};    // persistent zero C-operand

#define STAGE(tt, bb) do {                                                    \
        const uint4* gg = gbase + (size_t)(tt) * 1024 + w * 256 + lane;       \
        char* ldst = (char*)sbuf + (bb) * 16384 + w * 4096;                   \
        _Pragma("unroll")                                                     \
        for (int i_ = 0; i_ < 4; ++i_)                                        \
            gload16((const void*)(gg + i_ * 64), (void*)(ldst + i_ * 1024));  \
    } while (0)

    STAGE(0, 0);

    for (int t = 0; t < TILES_PER_CHUNK; ++t) {
        // Single barrier per tile. Pre-barrier vmcnt(0) drain covers STAGE(t)
        // (issued a full compute-phase ago -> ~no stall) and proves all waves
        // finished reading buf[(t+1)&1] (used at t-1) before we overwrite it.
        __syncthreads();
        if (t < TILES_PER_CHUNK - 1) STAGE(t + 1, (t + 1) & 1);
        const char* sbb = (const char*)sbuf + (t & 1) * 16384;

        #pragma unroll
        for (int sub = 0; sub < SUBT; ++sub) {
            uint4 ua0 = *(const uint4*)(sbb + base_b + sub * 2048);
            uint4 ua1 = *(const uint4*)(sbb + (base_b ^ 64) + sub * 2048);
            F16 a0, a1; a0.u = ua0; a1.u = ua1;
            uint32_t gid = (uint32_t)(t * SUBT + sub);   // 0..511

            #pragma unroll
            for (int j = 0; j < 2; ++j) {
                f32x4 acc = __builtin_amdgcn_mfma_f32_16x16x32_f16(a0.h, B[j][0], zacc, 0, 0, 0);
                acc = __builtin_amdgcn_mfma_f32_16x16x32_f16(a1.h, B[j][1], acc, 0, 0, 0);
                float m = fmaxf(fmaxf(acc[0], acc[1]), fmaxf(acc[2], acc[3]));
                if (m > m_[j][3]) {
                    bool b2 = m > m_[j][2], b1 = m > m_[j][1], b0 = m > m_[j][0];
                    m_[j][3] = b2 ? m_[j][2] : m;  g_[j][3] = b2 ? g_[j][2] : gid;
                    m_[j][2] = b2 ? (b1 ? m_[j][1] : m) : m_[j][2];
                    g_[j][2] = b2 ? (b1 ? g_[j][1] : gid) : g_[j][2];
                    m_[j][1] = b1 ? (b0 ? m_[j][0] : m) : m_[j][1];
                    g_[j][1] = b1 ? (b0 ? g_[j][0] : gid) : g_[j][1];
                    m_[j][0] = b0 ? m : m_[j][0];  g_[j][0] = b0 ? gid : g_[j][0];
                }
            }
        }
    }
#undef STAGE

    // merge top-4 groups across the 4 lane-rows; emit 4 group ids per (q,chunk)
    #pragma unroll
    for (int j = 0; j < 2; ++j) {
        uint64_t s4[4];
        #pragma unroll
        for (int e = 0; e < 4; ++e)
            s4[e] = ((uint64_t)ord32(m_[j][e]) << 32)
                  | (uint64_t)(g_[j][e] * 4 + (uint32_t)lrow);
        #pragma unroll
        for (int m = 16; m <= 32; m <<= 1) {
            uint64_t b0 = (uint64_t)__shfl_xor((unsigned long long)s4[0], m, 64);
            uint64_t b1 = (uint64_t)__shfl_xor((unsigned long long)s4[1], m, 64);
            uint64_t b2 = (uint64_t)__shfl_xor((unsigned long long)s4[2], m, 64);
            uint64_t b3 = (uint64_t)__shfl_xor((unsigned long long)s4[3], m, 64);
            merge4(s4, b0, b1, b2, b3);
        }
        if (lane < 16) {
            int q = qblock * QPB + w * 32 + j * 16 + lane;
            uint4 c;
            c.x = (uint32_t)s4[0]; c.y = (uint32_t)s4[1];
            c.z = (uint32_t)s4[2]; c.w = (uint32_t)s4[3];
            *(uint4*)&cand[((size_t)q * NCHUNK + chunk) * 4] = c;
        }
    }
}

// ---- exact f64 rescore of 128 candidates per query (1 wave / query) ----
__global__ __launch_bounds__(256) void k2_rescore(
        const uint32_t* __restrict__ cand,
        const float* __restrict__ queries, const float* __restrict__ keys,
        int* __restrict__ idx_int, float* __restrict__ idx_f) {
    int w = threadIdx.x >> 6, lane = threadIdx.x & 63;
    int q = blockIdx.x * 4 + w;
    const float4* qrow = (const float4*)(queries + (size_t)q * KEY_DIM);

    uint64_t s4[4] = {0ull, 0ull, 0ull, 0ull};
    #pragma unroll
    for (int half = 0; half < 2; ++half) {
        int c = lane + half * 64;               // candidate 0..127
        int chunk = c >> 4, e = (c >> 2) & 3, rr = c & 3;
        uint32_t grow = cand[((size_t)q * NCHUNK + chunk) * 4 + e];
        int slot = chunk * CHUNK + (int)(grow >> 2) * 16 + (int)(grow & 3) * 4 + rr;
        const float4* krow = (const float4*)(keys + (size_t)slot * KEY_DIM);
        double acc = 0.0;
        #pragma unroll
        for (int u = 0; u < 16; ++u) {
            float4 qv = qrow[u], kv = krow[u];
            acc = fma((double)qv.x, (double)kv.x, acc);
            acc = fma((double)qv.y, (double)kv.y, acc);
            acc = fma((double)qv.z, (double)kv.z, acc);
            acc = fma((double)qv.w, (double)kv.w, acc);
        }
        uint64_t key = (ord64(acc) & 0xFFFFFFFFFFFF0000ull)
                     | (uint64_t)((~(uint32_t)slot) & 0xFFFFu);
        ins4(s4, key);
    }
    #pragma unroll
    for (int m = 1; m <= 32; m <<= 1) {
        uint64_t b0 = (uint64_t)__shfl_xor((unsigned long long)s4[0], m, 64);
        uint64_t b1 = (uint64_t)__shfl_xor((unsigned long long)s4[1], m, 64);
        uint64_t b2 = (uint64_t)__shfl_xor((unsigned long long)s4[2], m, 64);
        uint64_t b3 = (uint64_t)__shfl_xor((unsigned long long)s4[3], m, 64);
        merge4(s4, b0, b1, b2, b3);
    }
    if (lane == 0) {
        #pragma unroll
        for (int r = 0; r < 4; ++r) {
            int s = (int)((~(uint32_t)s4[r]) & 0xFFFFu);
            idx_int[q * TOPK + r] = s;
            idx_f[q * TOPK + r] = (float)s;
        }
    }
}

__global__ void k3_gather_scatter(const int* __restrict__ idx_int,
                                  const float* __restrict__ vals,
                                  const float* __restrict__ grads,
                                  float* __restrict__ retrieved,
                                  float* __restrict__ slot_grads,
                                  float* __restrict__ counts) {
    int e = blockIdx.x * 256 + threadIdx.x;
    int qr = e >> 6;
    int d  = e & 63;
    int slot = idx_int[qr];
    retrieved[e] = vals[slot * VAL_DIM + d];
    atomicAdd(&slot_grads[slot * VAL_DIM + d], grads[e]);
    if (d == 0) atomicAdd(&counts[slot], 1.0f);
}

__global__ void k4_update(const float* __restrict__ vals,
                          const float* __restrict__ mom,
                          const float* __restrict__ slot_grads,
                          const float* __restrict__ counts,
                          float* __restrict__ new_vals,
                          float* __restrict__ new_mom) {
    int e = blockIdx.x * 256 + threadIdx.x;
    int slot = e >> 6;
    float c = counts[slot];
    float g = slot_grads[e];
    float avg = g / fmaxf(c, 1.0f);
    float nm = MOMENTUM * mom[e] + avg;
    float v = vals[e];
    float nv = v + ((c > 0.0f) ? (-LR * (nm + WD * v)) : 0.0f);
    new_vals[e] = nv;
    new_mom[e] = nm;
}

__global__ void k0_zero(float* __restrict__ p, int n) {
    int i = blockIdx.x * 256 + threadIdx.x;
    if (i < n) p[i] = 0.0f;
}

extern "C" void kernel_launch(void* const* d_in, const int* in_sizes, int n_in,
                              void* d_out, int out_size, void* d_ws, size_t ws_size,
                              hipStream_t stream) {
    const float* queries = (const float*)d_in[0];
    const float* grads   = (const float*)d_in[1];
    const float* keys    = (const float*)d_in[2];
    const float* vals    = (const float*)d_in[3];
    const float* mom     = (const float*)d_in[4];

    float* out = (float*)d_out;
    float* retrieved = out;
    float* idx_f     = retrieved + (size_t)N_QUERIES * TOPK * VAL_DIM;
    float* new_vals  = idx_f + (size_t)N_QUERIES * TOPK;
    float* new_mom   = new_vals + (size_t)N_SLOTS * VAL_DIM;

    float*    slot_grads = (float*)d_ws;                            // 16 MiB
    float*    counts     = slot_grads + (size_t)N_SLOTS * VAL_DIM;  // 256 KiB
    uint4*    qpack  = (uint4*)(counts + N_SLOTS);                  // 1 MiB
    uint4*    kpack  = qpack + (size_t)N_QUERIES * 8;               // 8 MiB
    uint32_t* cand   = (uint32_t*)(kpack + (size_t)(N_SLOTS / TILE_SLOTS) * 1024); // 1 MiB
    int*      idx_int = (int*)(cand + (size_t)N_QUERIES * NCHUNK * 4);             // 128 KiB

    int nzero = N_SLOTS * VAL_DIM + N_SLOTS;
    hipLaunchKernelGGL(k0_zero, dim3((nzero + 255) / 256), dim3(256), 0, stream,
                       slot_grads, nzero);
    hipLaunchKernelGGL(kA_split_q, dim3(N_QUERIES * 8 / 256), dim3(256), 0, stream,
                       queries, qpack);
    hipLaunchKernelGGL(kA_split_k, dim3(N_SLOTS * 8 / 256), dim3(256), 0, stream,
                       keys, kpack);
    hipLaunchKernelGGL(k1_screen, dim3(N_QUERIES / QPB, NCHUNK), dim3(256), 0, stream,
                       qpack, kpack, cand);
    hipLaunchKernelGGL(k2_rescore, dim3(N_QUERIES / 4), dim3(256), 0, stream,
                       cand, queries, keys, idx_int, idx_f);
    hipLaunchKernelGGL(k3_gather_scatter,
                       dim3(N_QUERIES * TOPK * VAL_DIM / 256), dim3(256), 0, stream,
                       idx_int, vals, grads, retrieved, slot_grads, counts);
    hipLaunchKernelGGL(k4_update, dim3(N_SLOTS * VAL_DIM / 256), dim3(256), 0, stream,
                       vals, mom, slot_grads, counts, new_vals, new_mom);
}